// Round 2
// baseline (578.288 us; speedup 1.0000x reference)
//
#include <hip/hip_runtime.h>
#include <stdint.h>
#include <stddef.h>

#define F_FIELDS 39
#define VOCAB    200000
#define EMB      16
#define BATCH    16384
#define MBLK     32      // samples per block
#define NOUT     64      // 32 first_order + 32 s
#define KPAD     640     // 624 padded to 640
#define NCHUNK   10
#define KC       64      // k per chunk = 4 fields
#define ASTR     88      // A_sh row stride (bf16 elems): 16B-aligned
#define BSTR     88      // B_sh row stride
#define CSTR     68      // C_sh row stride (f32)

typedef __attribute__((ext_vector_type(8))) short bf16x8;
typedef __attribute__((ext_vector_type(4))) float f32x4;

__device__ __forceinline__ unsigned short f2bf(float x) {
  union { float f; unsigned int u; } a; a.f = x;
  unsigned int r = (a.u + 0x7fffu + ((a.u >> 16) & 1u)) >> 16;
  return (unsigned short)r;
}
__device__ __forceinline__ float bf2f(unsigned short h) {
  union { unsigned int u; float f; } a; a.u = ((unsigned int)h) << 16;
  return a.f;
}

// Build Wt[n][k] bf16: n<32 -> W1[n][k], n>=32 -> Wi[n-32][k]; k in [624,640) = 0
__global__ void prep_w(const float* __restrict__ W1, const float* __restrict__ Wi,
                       unsigned short* __restrict__ Wt) {
  int i = blockIdx.x * 256 + threadIdx.x;
  if (i >= NOUT * KPAD) return;
  int n = i / KPAD, k = i % KPAD;
  float v = 0.0f;
  if (k < F_FIELDS * EMB) v = (n < 32) ? W1[n * 624 + k] : Wi[(n - 32) * 624 + k];
  Wt[i] = f2bf(v);
}

__global__ __launch_bounds__(256) void pnn_main(
    const int* __restrict__ Xi, const float* __restrict__ Xv,
    const float* __restrict__ tables, const unsigned short* __restrict__ Wt,
    const float* __restrict__ lin1_w, const float* __restrict__ lin1_b,
    const float* __restrict__ lin2_w, const float* __restrict__ lin2_b,
    const float* __restrict__ last_w, const float* __restrict__ last_b,
    float* __restrict__ out)
{
  const int t    = threadIdx.x;
  const int wave = t >> 6, lane = t & 63;
  const int l15  = lane & 15, quad = lane >> 4;

  __shared__ unsigned short A_sh[MBLK * ASTR];   //  5.5 KB  (hi part)
  __shared__ unsigned short Al_sh[MBLK * ASTR];  //  5.5 KB  (lo part)
  __shared__ unsigned short B_sh[NOUT * BSTR];   // 11   KB
  __shared__ float          C_sh[MBLK * CSTR];   //  8.5 KB
  __shared__ float          X1_sh[MBLK * 36];    //  4.5 KB
  __shared__ float          W_lds[2145];         //  8.4 KB  lin1|lin2|b1|b2|lastw|lastb

  // ---- stage MLP weights (used only after many syncs) ----
  for (int i = t; i < 1024; i += 256) {
    W_lds[i]        = lin1_w[i];
    W_lds[1024 + i] = lin2_w[i];
  }
  if (t < 32) {
    W_lds[2048 + t] = lin1_b[t];
    W_lds[2080 + t] = lin2_b[t];
    W_lds[2112 + t] = last_w[t];
  }
  if (t == 0) W_lds[2144] = last_b[0];

  // ---- gather mapping: thread -> (sample m, field-in-chunk fl, e-half) ----
  const int gm    = t & 31;
  const int gfl   = (t >> 5) & 3;
  const int ghalf = t >> 7;
  const int sample = blockIdx.x * MBLK + gm;

  int   idxs[NCHUNK];
  float xvs[NCHUNK];
#pragma unroll
  for (int c = 0; c < NCHUNK; ++c) {
    int f = c * 4 + gfl;
    bool v = (f < F_FIELDS);
    int g = sample * F_FIELDS + (v ? f : 0);
    idxs[c] = v ? Xi[g] : 0;
    xvs[c]  = v ? Xv[g] : 0.0f;
  }

  // ---- B staging mapping: 64 rows x 4 segs of 16 elems (32 B) each ----
  const int bn = t >> 2, bseg = t & 3;

  // ---- per-wave MFMA tile: 16 m x 32 n ----
  const int m_tile = wave & 1, n_half = wave >> 1;
  const int arow = m_tile * 16 + l15;
  const int nb0  = n_half * 32 + l15;

  f32x4 acc0 = {0.f, 0.f, 0.f, 0.f};
  f32x4 acc1 = {0.f, 0.f, 0.f, 0.f};

#pragma unroll
  for (int c = 0; c < NCHUNK; ++c) {
    // stage B chunk (64 n x 64 k bf16): 2x uint4 per thread
    {
      const uint4* src = (const uint4*)(Wt + bn * KPAD + c * KC + bseg * 16);
      uint4 w0 = src[0], w1 = src[1];
      uint4* dst = (uint4*)&B_sh[bn * BSTR + bseg * 16];
      dst[0] = w0; dst[1] = w1;
    }
    // gather A chunk (32 m x 64 k), scale by Xv, split hi/lo bf16
    {
      int f = c * 4 + gfl;
      float4 v0 = {0.f,0.f,0.f,0.f}, v1 = {0.f,0.f,0.f,0.f};
      float xv = xvs[c];
      if (f < F_FIELDS) {
        const float* p = tables + ((size_t)f * VOCAB + (size_t)idxs[c]) * EMB + ghalf * 8;
        v0 = *(const float4*)p;
        v1 = *(const float4*)(p + 4);
      }
      float vals[8] = { v0.x * xv, v0.y * xv, v0.z * xv, v0.w * xv,
                        v1.x * xv, v1.y * xv, v1.z * xv, v1.w * xv };
      union { unsigned short us[8]; uint4 v; } hi, lo;
#pragma unroll
      for (int j = 0; j < 8; ++j) {
        unsigned short h = f2bf(vals[j]);
        hi.us[j] = h;
        lo.us[j] = f2bf(vals[j] - bf2f(h));
      }
      *(uint4*)&A_sh[gm * ASTR + gfl * 16 + ghalf * 8]  = hi.v;
      *(uint4*)&Al_sh[gm * ASTR + gfl * 16 + ghalf * 8] = lo.v;
    }
    __syncthreads();
#pragma unroll
    for (int kk = 0; kk < 2; ++kk) {
      bf16x8 ah = *(const bf16x8*)&A_sh[arow * ASTR + kk * 32 + quad * 8];
      bf16x8 al = *(const bf16x8*)&Al_sh[arow * ASTR + kk * 32 + quad * 8];
      bf16x8 b0 = *(const bf16x8*)&B_sh[nb0 * BSTR + kk * 32 + quad * 8];
      bf16x8 b1 = *(const bf16x8*)&B_sh[(nb0 + 16) * BSTR + kk * 32 + quad * 8];
      acc0 = __builtin_amdgcn_mfma_f32_16x16x32_bf16(ah, b0, acc0, 0, 0, 0);
      acc1 = __builtin_amdgcn_mfma_f32_16x16x32_bf16(ah, b1, acc1, 0, 0, 0);
      acc0 = __builtin_amdgcn_mfma_f32_16x16x32_bf16(al, b0, acc0, 0, 0, 0);
      acc1 = __builtin_amdgcn_mfma_f32_16x16x32_bf16(al, b1, acc1, 0, 0, 0);
    }
    __syncthreads();
  }

  // ---- C -> LDS (D layout: row = quad*4+reg, col = lane&15) ----
  {
    int row_base = m_tile * 16 + quad * 4;
    int col0 = n_half * 32 + l15;
#pragma unroll
    for (int r = 0; r < 4; ++r) {
      C_sh[(row_base + r) * CSTR + col0]      = acc0[r];
      C_sh[(row_base + r) * CSTR + col0 + 16] = acc1[r];
    }
  }
  __syncthreads();

  // ---- x = first_order + s*s (in-place into cols 0..31) ----
  {
    int m = t >> 3, j0 = (t & 7) * 4;
#pragma unroll
    for (int j = 0; j < 4; ++j) {
      float fo = C_sh[m * CSTR + j0 + j];
      float s  = C_sh[m * CSTR + 32 + j0 + j];
      C_sh[m * CSTR + j0 + j] = fo + s * s;
    }
  }
  __syncthreads();

  // ---- layer 1: x1 = relu(x @ lin1_w.T + b1) ----
  {
    const int m = t >> 3, d0 = (t & 7) * 4;
    float a0 = W_lds[2048 + d0 + 0];
    float a1 = W_lds[2048 + d0 + 1];
    float a2 = W_lds[2048 + d0 + 2];
    float a3 = W_lds[2048 + d0 + 3];
#pragma unroll
    for (int j = 0; j < 32; ++j) {
      float xj = C_sh[m * CSTR + j];
      a0 = fmaf(W_lds[(d0 + 0) * 32 + j], xj, a0);
      a1 = fmaf(W_lds[(d0 + 1) * 32 + j], xj, a1);
      a2 = fmaf(W_lds[(d0 + 2) * 32 + j], xj, a2);
      a3 = fmaf(W_lds[(d0 + 3) * 32 + j], xj, a3);
    }
    X1_sh[m * 36 + d0 + 0] = fmaxf(a0, 0.0f);
    X1_sh[m * 36 + d0 + 1] = fmaxf(a1, 0.0f);
    X1_sh[m * 36 + d0 + 2] = fmaxf(a2, 0.0f);
    X1_sh[m * 36 + d0 + 3] = fmaxf(a3, 0.0f);
  }
  __syncthreads();

  // ---- layer 2: x2 = relu(x1 @ lin2_w.T + b2) -> C_sh cols 32..63 ----
  {
    const int m = t >> 3, d0 = (t & 7) * 4;
    float a0 = W_lds[2080 + d0 + 0];
    float a1 = W_lds[2080 + d0 + 1];
    float a2 = W_lds[2080 + d0 + 2];
    float a3 = W_lds[2080 + d0 + 3];
#pragma unroll
    for (int j = 0; j < 32; ++j) {
      float xj = X1_sh[m * 36 + j];
      a0 = fmaf(W_lds[1024 + (d0 + 0) * 32 + j], xj, a0);
      a1 = fmaf(W_lds[1024 + (d0 + 1) * 32 + j], xj, a1);
      a2 = fmaf(W_lds[1024 + (d0 + 2) * 32 + j], xj, a2);
      a3 = fmaf(W_lds[1024 + (d0 + 3) * 32 + j], xj, a3);
    }
    C_sh[m * CSTR + 32 + d0 + 0] = fmaxf(a0, 0.0f);
    C_sh[m * CSTR + 32 + d0 + 1] = fmaxf(a1, 0.0f);
    C_sh[m * CSTR + 32 + d0 + 2] = fmaxf(a2, 0.0f);
    C_sh[m * CSTR + 32 + d0 + 3] = fmaxf(a3, 0.0f);
  }
  __syncthreads();

  // ---- last: out[m] = x2 @ last_w.T + last_b ----
  if (t < MBLK) {
    float s = W_lds[2144];
#pragma unroll
    for (int j = 0; j < 32; ++j)
      s = fmaf(W_lds[2112 + j], C_sh[t * CSTR + 32 + j], s);
    out[blockIdx.x * MBLK + t] = s;
  }
}

extern "C" void kernel_launch(void* const* d_in, const int* in_sizes, int n_in,
                              void* d_out, int out_size, void* d_ws, size_t ws_size,
                              hipStream_t stream) {
  (void)in_sizes; (void)n_in; (void)out_size; (void)ws_size;
  const int*   Xi     = (const int*)d_in[0];
  const float* Xv     = (const float*)d_in[1];
  const float* tables = (const float*)d_in[2];
  const float* W1     = (const float*)d_in[3];
  const float* Wi     = (const float*)d_in[4];
  const float* l1w    = (const float*)d_in[5];
  const float* l1b    = (const float*)d_in[6];
  const float* l2w    = (const float*)d_in[7];
  const float* l2b    = (const float*)d_in[8];
  const float* lw     = (const float*)d_in[9];
  const float* lb     = (const float*)d_in[10];
  float* out = (float*)d_out;

  unsigned short* Wt = (unsigned short*)d_ws;  // 64*640 bf16 = 80 KB

  prep_w<<<dim3((NOUT * KPAD + 255) / 256), dim3(256), 0, stream>>>(W1, Wi, Wt);
  pnn_main<<<dim3(BATCH / MBLK), dim3(256), 0, stream>>>(
      Xi, Xv, tables, Wt, l1w, l1b, l2w, l2b, lw, lb, out);
}